// Round 13
// baseline (53.401 us; speedup 1.0000x reference)
//
#include <hip/hip_runtime.h>

// 4-level lifting wavelet, fully fused. R13: M=8 aligned-b128 design.
//  - M=8 pairs/thread: window = 16 pairs = 8 aligned 16B slots (b128 reads),
//    det out = 2 aligned b128, avg out = 2 coalesced nt dwordx4 direct to
//    global (32B lane stride covers full 128B lines).
//  - L0 reads x straight from global (circular wrap by mask; halo reads are
//    REAL data -> det0 exact everywhere). No staging. Garbage creep: det1
//    end 5 -> det2 end 8 -> L3 avg end 12 < discard 16. OK.
//  - LDS holds only det chains: det0 [0,544) det1 [544,816) det2 [816,952)
//    slots (15.2 KB) -> 8 blocks/CU = 32 waves/CU. Writes disjoint from
//    reads at every level -> NO WAR barriers: 3 __syncthreads total.
//  - XOR slot swizzle v^((v>>3)&7) (involution) makes stride-4-slot b128
//    reads and stride-2-slot writes conflict-free-equivalent.
#define BS    256
#define CHUNK 4096
#define HALO  256
#define NN    65536

typedef float f4 __attribute__((ext_vector_type(4)));

__device__ __forceinline__ int swz(int v) { return v ^ ((v >> 3) & 7); }

__device__ __forceinline__ void ntst4(float* dst, const float* src) {
  __builtin_nontemporal_store(*(const f4*)src, (f4*)dst);
}

// One lifting level over window pairs p0..p0+15 (in[0..31]), exact-state
// warm-up on pairs p0..p0+7, outputs pairs p0+8..p0+15 -> av[0..7], dv[0..7].
__device__ __forceinline__ void lift8(const float* __restrict__ in,
                                      const float* __restrict__ P6,
                                      const float* __restrict__ U6,
                                      float* __restrict__ av,
                                      float* __restrict__ dv) {
  const float P0 = P6[0], P1 = P6[1], P2 = P6[2], P3 = P6[3], P4 = P6[4], P5 = P6[5];
  const float U0 = U6[0], U1 = U6[1], U2 = U6[2], U3 = U6[3], U4 = U6[4], U5 = U6[5];
  float dd[6], aa[4], ff[2];
#pragma unroll
  for (int k = 0; k < 6; ++k)
    dd[k] = in[2 * (k + 2) + 1] - (P0 * in[2 * (k + 2)] + P1 * in[2 * (k + 1)] + P2 * in[2 * k]);
#pragma unroll
  for (int k = 0; k < 4; ++k)
    aa[k] = in[2 * (k + 4)] + (U0 * dd[k + 2] + U1 * dd[k + 1] + U2 * dd[k]);
#pragma unroll
  for (int k = 0; k < 2; ++k)
    ff[k] = dd[k + 4] - (P3 * aa[k + 2] + P4 * aa[k + 1] + P5 * aa[k]);
  float e1 = in[14], e2 = in[12];
  float d1 = dd[5], d2 = dd[4], a1 = aa[3], a2 = aa[2], f1 = ff[1], f2 = ff[0];
#pragma unroll
  for (int i = 8; i < 16; ++i) {
    float e0 = in[2 * i], o0 = in[2 * i + 1];
    float d0 = o0 - (P0 * e0 + P1 * e1 + P2 * e2);
    float a0 = e0 + (U0 * d0 + U1 * d1 + U2 * d2);
    float f0 = d0 - (P3 * a0 + P4 * a1 + P5 * a2);
    float b0 = a0 + (U3 * f0 + U4 * f1 + U5 * f2);
    av[i - 8] = b0; dv[i - 8] = f0;
    e2 = e1; e1 = e0; d2 = d1; d1 = d0; a2 = a1; a1 = a0; f2 = f1; f1 = f0;
  }
}

__global__ __launch_bounds__(BS, 7)
void wavelet_fused_kernel(const float* __restrict__ x,
                          const float* __restrict__ Pc,
                          const float* __restrict__ Uc,
                          float* __restrict__ out) {
  __shared__ __align__(16) float A[3808];   // 952 slots = 15.2 KB

  const int tid = threadIdx.x;
  const int cx  = blockIdx.x;   // chunk 0..15
  const int row = blockIdx.y;   // row 0..511
  const int S   = cx * CHUNK;

  float* z0 = out + (size_t)row * 32768 + (S >> 1);
  float* z1 = out + 16777216 + (size_t)row * 16384 + (S >> 2);
  float* z2 = out + 25165824 + (size_t)row * 8192 + (S >> 3);
  float* z3 = out + 29360128 + (size_t)row * 4096 + (S >> 4);
  float* z4 = out + 31457280 + (size_t)row * 4096 + (S >> 4);

  const f4* x4 = (const f4*)(x + (size_t)row * NN);
  const int mask = NN / 4 - 1;
  const int vb0  = ((S - HALO) >> 2) - 4;   // global f4 index of window slot -4

  // ---- L0: global x -> (z0 direct nt, det0 -> LDS [0,544)) ----
  {
    float in0[32], av[8], dv[8];
#pragma unroll
    for (int rep = 0; rep < 2; ++rep) {
      const int s = tid + 256 * rep;           // slots 0..271
      if (rep == 0 || tid < 16) {
#pragma unroll
        for (int j = 0; j < 8; ++j)
          *(f4*)&in0[4 * j] = x4[(vb0 + 4 * s + j) & mask];
        lift8(in0, Pc, Uc, av, dv);
        *(f4*)&A[4 * swz(2 * s)]     = *(const f4*)&dv[0];
        *(f4*)&A[4 * swz(2 * s + 1)] = *(const f4*)&dv[4];
        if (s >= 16) {                          // discard 128 pairs
          ntst4(z0 + 8 * (s - 16),     av);
          ntst4(z0 + 8 * (s - 16) + 4, av + 4);
        }
      }
    }
  }
  __syncthreads();   // (1) det0 ready

  // ---- L1: det0 [0,544) -> det1 [544,816), z1 direct ----
  if (tid < 136) {
    float in1[32], av[8], dv[8];
#pragma unroll
    for (int j = 0; j < 8; ++j) {
      int v = 4 * tid - 4 + j;  v = v < 0 ? 0 : v;
      *(f4*)&in1[4 * j] = *(const f4*)&A[4 * swz(v)];
    }
    lift8(in1, Pc + 6, Uc + 6, av, dv);
    *(f4*)&A[4 * swz(544 + 2 * tid)]     = *(const f4*)&dv[0];
    *(f4*)&A[4 * swz(544 + 2 * tid + 1)] = *(const f4*)&dv[4];
    if (tid >= 8) {                             // discard 64 pairs
      ntst4(z1 + 8 * (tid - 8),     av);
      ntst4(z1 + 8 * (tid - 8) + 4, av + 4);
    }
  }
  __syncthreads();   // (2) det1 ready

  // ---- L2: det1 [544,816) -> det2 [816,952), z2 direct ----
  if (tid < 68) {
    float in2[32], av[8], dv[8];
#pragma unroll
    for (int j = 0; j < 8; ++j) {
      int v = 544 + 4 * tid - 4 + j;            // >= 540, in-bounds; tid=0 garbage discarded
      *(f4*)&in2[4 * j] = *(const f4*)&A[4 * swz(v)];
    }
    lift8(in2, Pc + 12, Uc + 12, av, dv);
    *(f4*)&A[4 * swz(816 + 2 * tid)]     = *(const f4*)&dv[0];
    *(f4*)&A[4 * swz(816 + 2 * tid + 1)] = *(const f4*)&dv[4];
    if (tid >= 4) {                             // discard 32 pairs
      ntst4(z2 + 8 * (tid - 4),     av);
      ntst4(z2 + 8 * (tid - 4) + 4, av + 4);
    }
  }
  __syncthreads();   // (3) det2 ready

  // ---- L3: det2 [816,952) -> z3, z4 direct ----
  if (tid < 34) {
    float in3[32], av[8], dv[8];
#pragma unroll
    for (int j = 0; j < 8; ++j) {
      int v = 816 + 4 * tid - 4 + j;            // >= 812, in-bounds
      *(f4*)&in3[4 * j] = *(const f4*)&A[4 * swz(v)];
    }
    lift8(in3, Pc + 18, Uc + 18, av, dv);
    if (tid >= 2) {                             // discard 16 pairs
      ntst4(z3 + 8 * (tid - 2),     av);
      ntst4(z3 + 8 * (tid - 2) + 4, av + 4);
      ntst4(z4 + 8 * (tid - 2),     dv);
      ntst4(z4 + 8 * (tid - 2) + 4, dv + 4);
    }
  }
}

extern "C" void kernel_launch(void* const* d_in, const int* in_sizes, int n_in,
                              void* d_out, int out_size, void* d_ws, size_t ws_size,
                              hipStream_t stream) {
  const float* x  = (const float*)d_in[0];
  const float* Pc = (const float*)d_in[1];
  const float* Uc = (const float*)d_in[2];
  float* out = (float*)d_out;

  dim3 grid(NN / CHUNK, 512, 1);   // 16 x 512 = 8192 blocks
  dim3 block(BS, 1, 1);
  wavelet_fused_kernel<<<grid, block, 0, stream>>>(x, Pc, Uc, out);
}